// Round 5
// baseline (1021.017 us; speedup 1.0000x reference)
//
#include <hip/hip_runtime.h>
#include <hip/hip_bf16.h>
#include <math.h>

typedef unsigned short u16;
typedef __attribute__((ext_vector_type(8))) short short8;   // 8 bf16 (4 VGPRs)
typedef __attribute__((ext_vector_type(4))) float f32x4;    // MFMA C/D frag

// Problem constants: B=8, N=2048, D=DC=1024, K_centers=4, M = B*N = 16384.
//
// R4 algebra (kept): fr1 -> joint1(x_ring,h2) -> w -> joint2(gate,fch) -> fc2.
// R5: (a) double-buffered LDS in gemm128 (one barrier/iter; cp16s for iter
// k+1 issued before the MFMA phase of iter k, so the barrier's vmcnt(0)
// drain covers loads issued ~620 cyc earlier); (b) all weight transposes +
// fr_w2 cast merged into one prep_all launch; folds read fp32 originals
// coalesced (launch count 16 -> 9).

__device__ __forceinline__ float bf2f(u16 b) {
  return __uint_as_float(((unsigned int)b) << 16);
}
__device__ __forceinline__ u16 f2bf(float f) {
  unsigned int u = __float_as_uint(f);
  u += 0x7FFFu + ((u >> 16) & 1u);   // round-to-nearest-even (finite inputs)
  return (u16)(u >> 16);
}
__device__ __forceinline__ float gelu_exact(float x) {
  return 0.5f * x * (1.0f + erff(x * 0.70710678118654752f));
}

// async 16B/lane global->LDS. LDS dest is wave-uniform base + lane*16.
__device__ __forceinline__ void cp16(const void* g, void* l) {
  __builtin_amdgcn_global_load_lds(
      (const __attribute__((address_space(1))) unsigned int*)g,
      (__attribute__((address_space(3))) unsigned int*)l, 16, 0, 0);
}

// ---------------------------------------------------------------------------
// GEMM: C[M,Nout] = A[M,K](bf16) @ Wt[Nout,K]^T(bf16)  (Wt row-major [Nout,K])
// 128x128 tile, BK=64, 4 waves (2x2), each wave 64x64 via 4x4 of 16x16x32 MFMA.
// R5: ping-pong LDS (2 x (A16K+B16K) = 64 KB), ONE barrier per iteration.
// LDS quad-XOR swizzle keeps fragment ds_read_b128 <=2-way bank aliased.
// XCD swizzle: linear%8 -> XCD; compact m-range per XCD (R2: FETCH 935->200MB).
// GATHER=true implements the jnp.roll fusion for fr1.
// MODE: 0 = gelu -> bf16 out0 (ldo0)
//       4 = final: out0 f32 = p0(gate)*(v+bias) + (1-p0)*p1(xring)
//       6 = no bias, bf16 out0 (M2T precompute)
//       7 = joint1: n<1024: v+bias -> out1 f32 & out0 bf16;
//           n>=1024: gelu(v+bias2) -> out2 bf16
//       8 = joint2: n<1024: sigmoid(v+bias[n]+w.G2T[n]) -> out0 f32;
//           n>=1024: gelu(v+bias2[n']+w.F2T[n']) -> out1 bf16
//           (p0 = w[M,4], p1 = G2T[1024,4], p2 = F2T[1024,4])
// ---------------------------------------------------------------------------
template <int MODE, bool GATHER>
__global__ __launch_bounds__(256) void gemm128(
    const u16* __restrict__ A, int lda, const u16* __restrict__ Wt, int K,
    const float* __restrict__ bias, const float* __restrict__ bias2,
    void* __restrict__ out0, int ldo0, void* __restrict__ out1,
    void* __restrict__ out2, const float* __restrict__ p0,
    const float* __restrict__ p1, const float* __restrict__ p2) {
  __shared__ __align__(16) u16 As0[128 * 64];
  __shared__ __align__(16) u16 Bs0[128 * 64];
  __shared__ __align__(16) u16 As1[128 * 64];
  __shared__ __align__(16) u16 Bs1[128 * 64];

  const int tid = threadIdx.x;
  const int lane = tid & 63;
  const int wave = tid >> 6;     // 0..3
  const int wm = wave >> 1;      // wave row in 2x2
  const int wn = wave & 1;       // wave col

  // ---- XCD-aware block swizzle (gridDim.y divisible by 8) ----
  const unsigned linear = blockIdx.y * gridDim.x + blockIdx.x;
  const unsigned xcd = linear & 7u;
  const unsigned pos = linear >> 3;
  const unsigned bx = pos % gridDim.x;
  const unsigned by = xcd * (gridDim.y >> 3) + pos / gridDim.x;
  const int m0 = by * 128;
  const int n0 = bx * 128;

  const int srow = lane >> 3;    // 0..7: row within an 8-row staging chunk
  const int sq = lane & 7;       // quad (16B) within a 128B row
  const int sqs = sq ^ srow;     // swizzled global quad

  f32x4 acc[4][4];
#pragma unroll
  for (int i = 0; i < 4; i++)
#pragma unroll
    for (int j = 0; j < 4; j++) acc[i][j] = (f32x4){0.f, 0.f, 0.f, 0.f};

  auto stageA = [&](int k0, u16* buf) {
#pragma unroll
    for (int i = 0; i < 4; i++) {
      const int rloc = wave * 32 + i * 8 + srow;   // 0..127
      long gofs;
      if (GATHER) {
        const int seg = k0 >> 10;                  // uniform per iteration
        int shift;
        switch (seg) {
          case 0: shift = 1; break;
          case 1: shift = -1; break;
          case 2: shift = 0; break;
          case 3: shift = 2; break;
          case 4: shift = -2; break;
          case 5: shift = 4; break;
          default: shift = -4; break;
        }
        const int m = m0 + rloc;
        const int b = m >> 11;                     // N = 2048 = 2^11
        const int nsrc = ((m & 2047) - shift) & 2047;
        gofs = (long)((b << 11) | nsrc) * 1024 + (k0 & 1023) + sqs * 8;
      } else {
        gofs = (long)(m0 + rloc) * lda + k0 + sqs * 8;
      }
      cp16(A + gofs, &buf[(wave * 32 + i * 8) * 64]);
    }
  };
  auto stageB = [&](int k0, u16* buf) {
#pragma unroll
    for (int i = 0; i < 4; i++) {
      const int rloc = wave * 32 + i * 8 + srow;
      const long gofs = (long)(n0 + rloc) * K + k0 + sqs * 8;
      cp16(Wt + gofs, &buf[(wave * 32 + i * 8) * 64]);
    }
  };

  const int niter = K >> 6;
  stageA(0, As0);
  stageB(0, Bs0);
  u16* ar = As0; u16* br = Bs0;
  u16* aw = As1; u16* bw = Bs1;
  __syncthreads();   // drain prologue cp16s

  const int q4 = lane >> 4;     // 0..3
  const int r16 = lane & 15;
  for (int it = 0; it < niter; ++it) {
    if (it + 1 < niter) {        // prefetch next tiles into the other buffers
      stageA((it + 1) << 6, aw);
      stageB((it + 1) << 6, bw);
    }
    // compute on ar/br
#pragma unroll
    for (int kk = 0; kk < 2; kk++) {
      short8 af[4], bf[4];
#pragma unroll
      for (int mi = 0; mi < 4; mi++) {
        const int row = wm * 64 + mi * 16 + r16;
        const int q = (kk * 4 + q4) ^ (row & 7);
        af[mi] = *(const short8*)&ar[row * 64 + q * 8];
      }
#pragma unroll
      for (int ni = 0; ni < 4; ni++) {
        const int row = wn * 64 + ni * 16 + r16;
        const int q = (kk * 4 + q4) ^ (row & 7);
        bf[ni] = *(const short8*)&br[row * 64 + q * 8];
      }
#pragma unroll
      for (int mi = 0; mi < 4; mi++)
#pragma unroll
        for (int ni = 0; ni < 4; ni++)
          acc[mi][ni] = __builtin_amdgcn_mfma_f32_16x16x32_bf16(
              af[mi], bf[ni], acc[mi][ni], 0, 0, 0);
    }
    __syncthreads();   // publishes next tiles; drain covers old cp16s
    u16* t;
    t = ar; ar = aw; aw = t;
    t = br; br = bw; bw = t;
  }

  // epilogue: C/D layout col = lane&15, row = (lane>>4)*4 + reg
  const int ccol = r16;
  const int crow = q4 * 4;
#pragma unroll
  for (int mi = 0; mi < 4; mi++) {
#pragma unroll
    for (int r = 0; r < 4; r++) {
      const int m = m0 + wm * 64 + mi * 16 + crow + r;
      float4 wrow;
      if (MODE == 8) wrow = *(const float4*)(p0 + (size_t)m * 4);
#pragma unroll
      for (int ni = 0; ni < 4; ni++) {
        const int n = n0 + wn * 64 + ni * 16 + ccol;
        const float v = acc[mi][ni][r];
        if (MODE == 0) {
          ((u16*)out0)[(long)m * ldo0 + n] = f2bf(gelu_exact(v + bias[n]));
        } else if (MODE == 4) {
          const float g = p0[(long)m * 1024 + n];
          const float xr = p1[(long)m * 1024 + n];
          ((float*)out0)[(long)m * ldo0 + n] =
              g * (v + bias[n]) + (1.0f - g) * xr;
        } else if (MODE == 6) {
          ((u16*)out0)[(long)m * ldo0 + n] = f2bf(v);
        } else if (MODE == 7) {
          if (n < 1024) {
            const float s = v + bias[n];
            ((float*)out1)[(long)m * 1024 + n] = s;
            ((u16*)out0)[(long)m * 1024 + n] = f2bf(s);
          } else {
            const int nn = n - 1024;
            ((u16*)out2)[(long)m * 1024 + nn] = f2bf(gelu_exact(v + bias2[nn]));
          }
        } else if (MODE == 8) {
          if (n < 1024) {
            const float4 g2 = *(const float4*)(p1 + (size_t)n * 4);
            const float s = v + bias[n] + wrow.x * g2.x + wrow.y * g2.y +
                            wrow.z * g2.z + wrow.w * g2.w;
            ((float*)out0)[(long)m * 1024 + n] = 1.0f / (1.0f + expf(-s));
          } else {
            const int nn = n - 1024;
            const float4 f2 = *(const float4*)(p2 + (size_t)nn * 4);
            const float s = v + bias2[nn] + wrow.x * f2.x + wrow.y * f2.y +
                            wrow.z * f2.z + wrow.w * f2.w;
            ((u16*)out1)[(long)m * 1024 + nn] = f2bf(gelu_exact(s));
          }
        }
      }
    }
  }
}

// fp32 -> bf16 cast, 4 elems/thread
__global__ __launch_bounds__(256) void cast_bf16(const float* __restrict__ in,
                                                 u16* __restrict__ out, int n4) {
  const long i = (long)blockIdx.x * 256 + threadIdx.x;
  if (i < n4) {
    const float4 v = ((const float4*)in)[i];
    ushort4 o;
    o.x = f2bf(v.x); o.y = f2bf(v.y); o.z = f2bf(v.z); o.w = f2bf(v.w);
    ((ushort4*)out)[i] = o;
  }
}

// One 32x32 transpose tile: in fp32 [.,N] rows r0.., cols c0.. -> out bf16 [N,K]
__device__ __forceinline__ void transp_tile(const float* __restrict__ in,
                                            u16* __restrict__ out, int K, int N,
                                            int bx, int by, float (*tile)[33],
                                            int tid) {
  const int tx = tid & 31;
  const int ty = tid >> 5;  // 0..7
  const long r0 = (long)by * 32;
  const long c0 = (long)bx * 32;
#pragma unroll
  for (int r = 0; r < 4; r++)
    tile[ty + r * 8][tx] = in[(r0 + ty + r * 8) * N + c0 + tx];
  __syncthreads();
#pragma unroll
  for (int r = 0; r < 4; r++)
    out[(c0 + ty + r * 8) * K + r0 + tx] = f2bf(tile[tx][ty + r * 8]);
}

// All weight preprocessing in ONE launch (13312 blocks):
//  [0,7168):      fr_w1 [7168,1024]   -> Wt1  (bf16 ^T)
//  [7168,8192):   fr_w2 [1024,1024]   -> WtJ lower half
//  [8192,9216):   tc_w1               -> Wt3
//  [9216,10240):  fc_w2               -> Wt6
//  [10240,11264): g_w rows 0..1023    -> WtG2 lower half
//  [11264,12288): fc_w1 rows 0..1023  -> WtG2 upper half
//  [12288,13312): fr_w2 cast (row-major bf16) -> Fw2b
__global__ __launch_bounds__(256) void prep_all(
    const float* __restrict__ fr_w1, const float* __restrict__ fr_w2,
    const float* __restrict__ tc_w1, const float* __restrict__ fc_w2,
    const float* __restrict__ g_w, const float* __restrict__ fc_w1,
    u16* __restrict__ Wt1, u16* __restrict__ WtJ, u16* __restrict__ Wt3,
    u16* __restrict__ Wt6, u16* __restrict__ WtG2, u16* __restrict__ Fw2b) {
  __shared__ float tile[32][33];
  const int b = blockIdx.x;
  const int tid = threadIdx.x;
  if (b < 7168) {
    transp_tile(fr_w1, Wt1, 7168, 1024, b & 31, b >> 5, tile, tid);
  } else if (b < 8192) {
    const int t = b - 7168;
    transp_tile(fr_w2, WtJ, 1024, 1024, t & 31, t >> 5, tile, tid);
  } else if (b < 9216) {
    const int t = b - 8192;
    transp_tile(tc_w1, Wt3, 1024, 1024, t & 31, t >> 5, tile, tid);
  } else if (b < 10240) {
    const int t = b - 9216;
    transp_tile(fc_w2, Wt6, 1024, 1024, t & 31, t >> 5, tile, tid);
  } else if (b < 11264) {
    const int t = b - 10240;
    transp_tile(g_w, WtG2, 1024, 1024, t & 31, t >> 5, tile, tid);
  } else if (b < 12288) {
    const int t = b - 11264;
    transp_tile(fc_w1, WtG2 + (size_t)1024 * 1024, 1024, 1024, t & 31, t >> 5,
                tile, tid);
  } else {
    const long i = (long)(b - 12288) * 256 + tid;   // float4 index
    const float4 v = ((const float4*)fr_w2)[i];
    ushort4 o;
    o.x = f2bf(v.x); o.y = f2bf(v.y); o.z = f2bf(v.z); o.w = f2bf(v.w);
    ((ushort4*)Fw2b)[i] = o;
  }
}

// Small folds, coalesced from fp32 originals (265 blocks):
//  [0,4):   n=b*256+tid: G2T[n][k] = sum_e centers[k][e]*g_w[1024+e][n]
//                        F2T[n][k] = sum_e centers[k][e]*fc_w1[1024+e][n]
//  [4,8):   j=...: c2[j] = sum_e fr_b2[e]*tc_w1[e][j] + tc_b1[j]
//  [8,264): d: S[k*1024+d] = sum_e tc_w2[d][e]*centers[k][e]
//  264:     k=wave: bc[k] = sum_e tc_b2[e]*centers[k][e]
__global__ __launch_bounds__(256) void fold_all(
    const float* __restrict__ g_w, const float* __restrict__ fc_w1,
    const float* __restrict__ tc_w1, const float* __restrict__ centers,
    const float* __restrict__ fr_b2, const float* __restrict__ tc_b1,
    const float* __restrict__ tc_w2, const float* __restrict__ tc_b2,
    float* __restrict__ G2T, float* __restrict__ F2T, float* __restrict__ c2,
    float* __restrict__ S, float* __restrict__ bc) {
  const int b = blockIdx.x;
  const int tid = threadIdx.x;
  if (b < 4) {
    const int n = b * 256 + tid;
    float g[4] = {0.f, 0.f, 0.f, 0.f}, f[4] = {0.f, 0.f, 0.f, 0.f};
    for (int e = 0; e < 1024; e++) {
      const float gv = g_w[(size_t)(1024 + e) * 1024 + n];
      const float fv = fc_w1[(size_t)(1024 + e) * 1024 + n];
#pragma unroll
      for (int k = 0; k < 4; k++) {
        const float c = centers[k * 1024 + e];
        g[k] += gv * c;
        f[k] += fv * c;
      }
    }
#pragma unroll
    for (int k = 0; k < 4; k++) {
      G2T[n * 4 + k] = g[k];
      F2T[n * 4 + k] = f[k];
    }
  } else if (b < 8) {
    const int j = (b - 4) * 256 + tid;
    float s = 0.f;
    for (int e = 0; e < 1024; e++) s += fr_b2[e] * tc_w1[(size_t)e * 1024 + j];
    c2[j] = s + tc_b1[j];
  } else if (b < 264) {
    const int wave = tid >> 6, lane = tid & 63;
    const int d = (b - 8) * 4 + wave;
    const float* row = tc_w2 + (long)d * 1024;
    float s0 = 0.f, s1 = 0.f, s2 = 0.f, s3 = 0.f;
    for (int e = lane; e < 1024; e += 64) {
      const float w = row[e];
      s0 += w * centers[e];
      s1 += w * centers[1024 + e];
      s2 += w * centers[2048 + e];
      s3 += w * centers[3072 + e];
    }
#pragma unroll
    for (int off = 32; off > 0; off >>= 1) {
      s0 += __shfl_xor(s0, off);
      s1 += __shfl_xor(s1, off);
      s2 += __shfl_xor(s2, off);
      s3 += __shfl_xor(s3, off);
    }
    if (lane == 0) {
      S[d] = s0; S[1024 + d] = s1; S[2048 + d] = s2; S[3072 + d] = s3;
    }
  } else {
    const int wave = tid >> 6, lane = tid & 63;
    const int k = wave;
    float s = 0.f;
    for (int e = lane; e < 1024; e += 64) s += tc_b2[e] * centers[k * 1024 + e];
#pragma unroll
    for (int off = 32; off > 0; off >>= 1) s += __shfl_xor(s, off);
    if (lane == 0) bc[k] = s;
  }
}

// w = softmax(h2 @ S^T + bc) over 4 centers; one wave per token -> w[t][0..3]
__global__ __launch_bounds__(256) void centers_kernel(
    const u16* __restrict__ h2, const float* __restrict__ S,
    const float* __restrict__ bc, float* __restrict__ wtok) {
  const int lane = threadIdx.x & 63;
  const int wave = threadIdx.x >> 6;
  const long t = (long)blockIdx.x * 4 + wave;
  const u16* row = h2 + t * 1024;
  float d0 = 0.f, d1 = 0.f, d2 = 0.f, d3 = 0.f;
#pragma unroll
  for (int j = 0; j < 2; j++) {
    const int dbase = j * 512 + lane * 8;
    const short8 v = *(const short8*)(row + dbase);
#pragma unroll
    for (int e = 0; e < 8; e++) {
      const float x = bf2f((u16)v[e]);
      const int d = dbase + e;
      d0 += x * S[d];
      d1 += x * S[1024 + d];
      d2 += x * S[2048 + d];
      d3 += x * S[3072 + d];
    }
  }
#pragma unroll
  for (int off = 32; off > 0; off >>= 1) {
    d0 += __shfl_xor(d0, off);
    d1 += __shfl_xor(d1, off);
    d2 += __shfl_xor(d2, off);
    d3 += __shfl_xor(d3, off);
  }
  if (lane == 0) {
    d0 += bc[0]; d1 += bc[1]; d2 += bc[2]; d3 += bc[3];
    const float mx = fmaxf(fmaxf(d0, d1), fmaxf(d2, d3));
    float e0 = expf(d0 - mx), e1 = expf(d1 - mx), e2 = expf(d2 - mx),
          e3 = expf(d3 - mx);
    const float inv = 1.0f / (e0 + e1 + e2 + e3);
    *(float4*)(wtok + t * 4) = (float4){e0 * inv, e1 * inv, e2 * inv, e3 * inv};
  }
}

extern "C" void kernel_launch(void* const* d_in, const int* in_sizes, int n_in,
                              void* d_out, int out_size, void* d_ws,
                              size_t ws_size, hipStream_t stream) {
  const float* queries = (const float*)d_in[0];
  const float* fr_w1 = (const float*)d_in[1];
  const float* fr_b1 = (const float*)d_in[2];
  const float* fr_w2 = (const float*)d_in[3];
  const float* fr_b2 = (const float*)d_in[4];
  const float* tc_w1 = (const float*)d_in[5];
  const float* tc_b1 = (const float*)d_in[6];
  const float* tc_w2 = (const float*)d_in[7];
  const float* tc_b2 = (const float*)d_in[8];
  const float* centers = (const float*)d_in[9];
  const float* fc_w1 = (const float*)d_in[10];
  const float* fc_b1 = (const float*)d_in[11];
  const float* fc_w2 = (const float*)d_in[12];
  const float* fc_b2 = (const float*)d_in[13];
  const float* g_w = (const float*)d_in[14];
  const float* g_b = (const float*)d_in[15];

  char* ws = (char*)d_ws;
  u16* Wt1 = (u16*)ws; ws += (size_t)7168 * 1024 * 2;   // fr_w1^T
  u16* Wt3 = (u16*)ws; ws += (size_t)1024 * 1024 * 2;   // tc_w1^T
  u16* Wt6 = (u16*)ws; ws += (size_t)1024 * 1024 * 2;   // fc_w2^T
  u16* WtJ = (u16*)ws; ws += (size_t)2048 * 1024 * 2;   // [fr_w2^T ; M2^T]
  u16* WtG2 = (u16*)ws; ws += (size_t)2048 * 1024 * 2;  // [g_w_top^T ; fc_w1_top^T]
  u16* Fw2b = (u16*)ws; ws += (size_t)1024 * 1024 * 2;  // fr_w2 bf16 (row-major)
  u16* Xb = (u16*)ws;  ws += (size_t)16384 * 1024 * 2;  // bf16 queries -> h2
  u16* h1 = (u16*)ws;  ws += (size_t)16384 * 1024 * 2;  // ring hidden -> fch
  u16* xrb = (u16*)ws; ws += (size_t)16384 * 1024 * 2;  // x_ring bf16
  float* xring = (float*)ws; ws += (size_t)16384 * 1024 * 4;  // x_ring f32
  float* wtok = (float*)ws; ws += (size_t)16384 * 4 * 4;      // softmax weights
  float* S = (float*)ws; ws += (size_t)4 * 1024 * 4;
  float* G2T = (float*)ws; ws += (size_t)1024 * 4 * 4;
  float* F2T = (float*)ws; ws += (size_t)1024 * 4 * 4;
  float* c2 = (float*)ws; ws += (size_t)1024 * 4;
  float* bc = (float*)ws; ws += 16;
  float* gate = (float*)d_out;  // gate f32 in d_out (read-then-overwrite)
  float* out = (float*)d_out;

  // --- preprocessing: 3 launches ---
  cast_bf16<<<16384, 256, 0, stream>>>(queries, Xb, 16384 * 1024 / 4);
  prep_all<<<13312, 256, 0, stream>>>(fr_w1, fr_w2, tc_w1, fc_w2, g_w, fc_w1,
                                      Wt1, WtJ, Wt3, Wt6, WtG2, Fw2b);
  fold_all<<<265, 256, 0, stream>>>(g_w, fc_w1, tc_w1, centers, fr_b2, tc_b1,
                                    tc_w2, tc_b2, G2T, F2T, c2, S, bc);
  // M2^T = (fr_w2 @ tc_w1)^T via GEMM: C[j][a] = sum_e Wt3[j][e]*Fw2b[a][e]
  gemm128<6, false><<<dim3(8, 8), 256, 0, stream>>>(
      Wt3, 1024, Fw2b, 1024, nullptr, nullptr, WtJ + (size_t)1024 * 1024, 1024,
      nullptr, nullptr, nullptr, nullptr, nullptr);

  // --- main chain ---
  // fr1: h1 = gelu(ring_gather(x) @ fr_w1 + fr_b1)
  gemm128<0, true><<<dim3(8, 128), 256, 0, stream>>>(
      Xb, 0, Wt1, 7168, fr_b1, nullptr, h1, 1024, nullptr, nullptr, nullptr,
      nullptr, nullptr);
  // joint1: x_ring (f32 + bf16) and h2 in one pass over h1
  gemm128<7, false><<<dim3(16, 128), 256, 0, stream>>>(
      h1, 1024, WtJ, 1024, fr_b2, c2, xrb, 1024, xring, Xb, nullptr, nullptr,
      nullptr);
  // w = softmax(h2 @ S^T + bc)
  centers_kernel<<<4096, 256, 0, stream>>>(Xb, S, bc, wtok);
  // joint2: gate -> d_out, fch -> h1 (w-corrections in epilogue)
  gemm128<8, false><<<dim3(16, 128), 256, 0, stream>>>(
      xrb, 1024, WtG2, 1024, g_b, fc_b1, gate, 1024, h1, nullptr, wtok, G2T,
      F2T);
  // fc2 + final mix: out = gate*(fch @ fc_w2 + fc_b2) + (1-gate)*x_ring
  gemm128<4, false><<<dim3(8, 128), 256, 0, stream>>>(
      h1, 1024, Wt6, 1024, fc_b2, nullptr, out, 1024, nullptr, nullptr, gate,
      xring, nullptr);
}